// Round 5
// baseline (1168.542 us; speedup 1.0000x reference)
//
#include <hip/hip_runtime.h>
#include <math.h>

#define T_STEPS 12
#define HID 64
#define NODES 10          // nodes per wave in gru_all
#define WPB 8             // waves per block
#define BLOCK (WPB*64)    // 512 threads
#define NPB (WPB*NODES)   // 80 nodes per block

__device__ __forceinline__ float sigmoidf_(float x){ return 1.0f/(1.0f + __expf(-x)); }
__device__ __forceinline__ float tanhf_(float x){
  float e = __expf(-2.0f * fabsf(x));
  float t = (1.0f - e) / (1.0f + e);
  return copysignf(t, x);
}
// broadcast lane l of v to all lanes via v_readlane (uniform l, no LDS pipe)
__device__ __forceinline__ float rlane(float v, int l){
  return __int_as_float(__builtin_amdgcn_readlane(__float_as_int(v), l));
}

// --- degree + norm ------------------------------------------------------
__global__ void count_kernel(const int* __restrict__ ei, int E, int* __restrict__ cnt){
  int e = blockIdx.x*blockDim.x + threadIdx.x;
  if (e < E) atomicAdd(&cnt[ei[E + e]], 1);
}

__global__ void dinv_kernel(const int* __restrict__ cnt, float* __restrict__ dinv, int N){
  int i = blockIdx.x*blockDim.x + threadIdx.x;
  if (i < N) dinv[i] = 1.0f / sqrtf((float)cnt[i] + 1.0f);
}

// Edge-parallel scatter in INPUT space (2 ch x 12 t = 24 floats per node).
// Thread = (edge, 4-channel chunk). rin[dst] += dinv[src] * x[src]  (dinv[dst] in fixup)
__global__ void scatter_kernel(const int* __restrict__ ei, int E,
                               const float* __restrict__ dinv,
                               const float* __restrict__ x,
                               float* __restrict__ rin){
  int tid = blockIdx.x*blockDim.x + threadIdx.x;
  if (tid >= E*6) return;
  int e = tid / 6;
  int part = tid - e*6;
  int src = ei[e];
  int dst = ei[E + e];
  float w = dinv[src];
  const float4* x4 = (const float4*)x;
  float4 v = x4[src*6 + part];
  float* base = rin + (size_t)dst*24 + part*4;
  atomicAdd(base + 0, w*v.x);
  atomicAdd(base + 1, w*v.y);
  atomicAdd(base + 2, w*v.z);
  atomicAdd(base + 3, w*v.w);
}

// rin[n][c] = dinv[n]*agg[n][c] + dinv[n]^2 * x[n][c]
__global__ void fixup_kernel(const float* __restrict__ x, const float* __restrict__ dinv,
                             float* __restrict__ rin, int N){
  int tid = blockIdx.x*blockDim.x + threadIdx.x;
  if (tid >= N*24) return;
  int n = tid / 24;
  float dn = dinv[n];
  rin[tid] = dn*rin[tid] + dn*dn*x[tid];
}

// Pack W_ih/W_hh (each 192x64 row-major) into 3 plane regions of float4[32*64]:
//   plane A (p*64+j):        {ir(k0), iz(k0), in(k0), hr(k0)}   -> LDS
//   plane B (2048 + p*64+j): {hz(k0), hn(k0), ir(k1), iz(k1)}   -> streamed (L2)
//   plane C (4096 + p*64+j): {in(k1), hr(k1), hz(k1), hn(k1)}   -> streamed (L2)
// gate index cc: 0=ih_r 1=ih_z 2=ih_n 3=hh_r 4=hh_z 5=hh_n ; k0=2p, k1=2p+1
__global__ void pack_kernel(const float* __restrict__ W_ih, const float* __restrict__ W_hh,
                            float* __restrict__ Wp){
  int idx = blockIdx.x*blockDim.x + threadIdx.x; // 0..24575
  if (idx >= 96*64*4) return;
  int f = idx & 3;
  int j = (idx >> 2) & 63;
  int q = idx >> 8;          // 0..95
  int plane = q >> 5;
  int p = q & 31;
  int c = plane*4 + f;
  int k  = 2*p + (c >= 6 ? 1 : 0);
  int cc = c % 6;
  float val;
  if (cc < 3) val = W_ih[(cc*HID + j)*HID + k];
  else        val = W_hh[((cc-3)*HID + j)*HID + k];
  Wp[idx] = val;
}

// All 12 GRU steps + final FC, fused. Wave = NODES nodes; lane j = channel j.
// h stays in registers. Plane A in LDS; planes B,C streamed from L2 with 1-deep
// prefetch. Broadcasts via v_readlane.
// amdgpu_waves_per_eu(2,4): allocator plans <=4 waves/EU -> 128-VGPR budget.
// (launch_bounds 2nd arg is a MIN waves/EU — it can only shrink the budget;
//  rounds 3/4 proved it leaves the 64-VGPR/8-wave default in place.)
__global__ __attribute__((amdgpu_waves_per_eu(2, 4))) __launch_bounds__(BLOCK)
void gru_all_kernel(
    const float* __restrict__ rin,
    const float* __restrict__ W_gcn, const float* __restrict__ b_gcn,
    const float* __restrict__ Wp,
    const float* __restrict__ b_ih, const float* __restrict__ b_hh,
    const float* __restrict__ W_fc, const float* __restrict__ b_fc,
    float* __restrict__ out, int N){
  __shared__ float4 wlds[2048];   // 32 KB: plane A
  const float4* Wp4 = (const float4*)Wp;
  #pragma unroll
  for (int i = 0; i < 2048/BLOCK; ++i)
    wlds[i*BLOCK + threadIdx.x] = Wp4[i*BLOCK + threadIdx.x];
  __syncthreads();

  int lane = threadIdx.x & 63;
  int wid  = threadIdx.x >> 6;
  int n0 = blockIdx.x*NPB + wid*NODES;
  if (n0 >= N) return;

  float wg0 = W_gcn[lane], wg1 = W_gcn[HID+lane], bg = b_gcn[lane];
  float brz_r = b_ih[lane]       + b_hh[lane];
  float brz_z = b_ih[HID+lane]   + b_hh[HID+lane];
  float bin   = b_ih[2*HID+lane];
  float bhn   = b_hh[2*HID+lane];

  const float4* WB = Wp4 + 2048;
  const float4* WC = Wp4 + 4096;

  float h[NODES];
  #pragma unroll
  for (int i = 0; i < NODES; ++i) h[i] = 0.f;

  #pragma unroll 1
  for (int t = 0; t < T_STEPS; ++t){
    float s[NODES];
    #pragma unroll
    for (int i = 0; i < NODES; ++i){
      int n = n0 + i;
      float r0 = (n < N) ? rin[n*24 + 2*t]     : 0.f;
      float r1 = (n < N) ? rin[n*24 + 2*t + 1] : 0.f;
      s[i] = fmaxf(fmaf(r0, wg0, fmaf(r1, wg1, bg)), 0.f);
    }

    float ar[NODES], az[NODES], ani[NODES], anh[NODES];
    #pragma unroll
    for (int i = 0; i < NODES; ++i){ ar[i]=0.f; az[i]=0.f; ani[i]=0.f; anh[i]=0.f; }

    float4 w1 = WB[lane];  // prefetch p=0
    float4 w2 = WC[lane];
    #pragma unroll 1
    for (int p = 0; p < 32; ++p){
      float4 w0 = wlds[p*64 + lane];
      float4 w1n, w2n;
      if (p < 31){ w1n = WB[(p+1)*64 + lane]; w2n = WC[(p+1)*64 + lane]; }
      else       { w1n = w1; w2n = w2; }
      int k0 = 2*p, k1 = 2*p + 1;
      #pragma unroll
      for (int i = 0; i < NODES; ++i){
        float sk0 = rlane(s[i], k0);
        float hk0 = rlane(h[i], k0);
        ar[i]  = fmaf(w0.x, sk0, ar[i]);
        az[i]  = fmaf(w0.y, sk0, az[i]);
        ani[i] = fmaf(w0.z, sk0, ani[i]);
        ar[i]  = fmaf(w0.w, hk0, ar[i]);
        az[i]  = fmaf(w1.x, hk0, az[i]);
        anh[i] = fmaf(w1.y, hk0, anh[i]);
        float sk1 = rlane(s[i], k1);
        float hk1 = rlane(h[i], k1);
        ar[i]  = fmaf(w1.z, sk1, ar[i]);
        az[i]  = fmaf(w1.w, sk1, az[i]);
        ani[i] = fmaf(w2.x, sk1, ani[i]);
        ar[i]  = fmaf(w2.y, hk1, ar[i]);
        az[i]  = fmaf(w2.z, hk1, az[i]);
        anh[i] = fmaf(w2.w, hk1, anh[i]);
      }
      w1 = w1n; w2 = w2n;
    }

    #pragma unroll
    for (int i = 0; i < NODES; ++i){
      float r  = sigmoidf_(ar[i] + brz_r);
      float z  = sigmoidf_(az[i] + brz_z);
      float nn = tanhf_(ani[i] + bin + r*(anh[i] + bhn));
      h[i] = (1.0f - z)*nn + z*h[i];
    }
  }

  // fused FC
  float wfc = W_fc[lane];
  float bfc = b_fc[0];
  #pragma unroll
  for (int i = 0; i < NODES; ++i){
    float v = h[i] * wfc;
    #pragma unroll
    for (int m = 32; m >= 1; m >>= 1) v += __shfl_xor(v, m, 64);
    int n = n0 + i;
    if (lane == 0 && n < N) out[n] = v + bfc;
  }
}

extern "C" void kernel_launch(void* const* d_in, const int* in_sizes, int n_in,
                              void* d_out, int out_size, void* d_ws, size_t ws_size,
                              hipStream_t stream){
  const float* x     = (const float*)d_in[0];
  const int*   ei    = (const int*)d_in[1];
  const float* W_gcn = (const float*)d_in[2];
  const float* b_gcn = (const float*)d_in[3];
  const float* W_ih  = (const float*)d_in[4];
  const float* W_hh  = (const float*)d_in[5];
  const float* b_ih  = (const float*)d_in[6];
  const float* b_hh  = (const float*)d_in[7];
  const float* W_fc  = (const float*)d_in[8];
  const float* b_fc  = (const float*)d_in[9];
  float* out = (float*)d_out;
  const int N = in_sizes[0] / (T_STEPS*2);
  const int E = in_sizes[1] / 2;

  char* p = (char*)d_ws;
  auto alloc = [&](size_t bytes)->char*{
    char* r = p; p += (bytes + 255) & ~(size_t)255; return r;
  };
  int*   cnt  = (int*)  alloc((size_t)N*4);
  float* dinv = (float*)alloc((size_t)N*4);
  float* Wp   = (float*)alloc((size_t)96*64*4*4);
  float* rin  = (float*)alloc((size_t)N*24*4);

  hipMemsetAsync(cnt, 0, (size_t)N*4, stream);
  hipMemsetAsync(rin, 0, (size_t)N*24*4, stream);
  count_kernel<<<(E+255)/256, 256, 0, stream>>>(ei, E, cnt);
  dinv_kernel<<<(N+255)/256, 256, 0, stream>>>(cnt, dinv, N);
  pack_kernel<<<(96*64*4+255)/256, 256, 0, stream>>>(W_ih, W_hh, Wp);
  scatter_kernel<<<(E*6+255)/256, 256, 0, stream>>>(ei, E, dinv, x, rin);
  fixup_kernel<<<(N*24+255)/256, 256, 0, stream>>>(x, dinv, rin, N);

  int blocks = (N + NPB - 1) / NPB;
  gru_all_kernel<<<blocks, BLOCK, 0, stream>>>(rin, W_gcn, b_gcn, Wp, b_ih, b_hh,
                                               W_fc, b_fc, out, N);
}

// Round 6
// 476.891 us; speedup vs baseline: 2.4503x; 2.4503x over previous
//
#include <hip/hip_runtime.h>
#include <math.h>

#define T_STEPS 12
#define HID 64
#define GWPB 6              // gru waves per block
#define GBLOCK (GWPB*64)    // 384 threads
#define XSTRIDE 132         // fp32 row stride for X tile (128 + 4 pad, breaks bank conflicts)
#define XWSZ (16*XSTRIDE)   // floats per wave X region
#define B_LDS_BYTES 98304   // 48 frag-slots x 1KB x {hi,lo}
#define X_LDS_BYTES (GWPB*XWSZ*4)
#define RIN_LDS_BYTES (GWPB*16*24*4)
#define LDS_TOTAL (B_LDS_BYTES + X_LDS_BYTES + RIN_LDS_BYTES)  // 158208 <= 160 KiB

typedef __attribute__((ext_vector_type(8))) short short8;
typedef __attribute__((ext_vector_type(4))) float floatx4;

__device__ __forceinline__ float sigmoidf_(float x){ return 1.0f/(1.0f + __expf(-x)); }
__device__ __forceinline__ float tanhf_(float x){
  float e = __expf(-2.0f * fabsf(x));
  float t = (1.0f - e) / (1.0f + e);
  return copysignf(t, x);
}
__device__ __forceinline__ unsigned short f2bf(float x){
  unsigned int u = __float_as_uint(x);
  unsigned int r = (u + 0x7FFFu + ((u >> 16) & 1u)) >> 16;  // RNE
  return (unsigned short)r;
}
__device__ __forceinline__ float bf2f(unsigned short h){
  return __uint_as_float(((unsigned int)h) << 16);
}

// --- CSR build (r4-proven) ---------------------------------------------
__global__ void count_kernel(const int* __restrict__ ei, int E, int* __restrict__ cnt){
  int e = blockIdx.x*blockDim.x + threadIdx.x;
  if (e < E) atomicAdd(&cnt[ei[E + e]], 1);
}
__global__ void dinv_kernel(const int* __restrict__ cnt, float* __restrict__ dinv, int N){
  int i = blockIdx.x*blockDim.x + threadIdx.x;
  if (i < N) dinv[i] = 1.0f / sqrtf((float)cnt[i] + 1.0f);
}
__global__ void scan1_kernel(const int* __restrict__ cnt, int* __restrict__ part,
                             int* __restrict__ bsum, int N){
  __shared__ int sm[1024];
  int tid = threadIdx.x;
  int g = blockIdx.x*1024 + tid;
  int v = (g < N) ? cnt[g] : 0;
  sm[tid] = v; __syncthreads();
  for (int off = 1; off < 1024; off <<= 1){
    int t = (tid >= off) ? sm[tid-off] : 0;
    __syncthreads();
    sm[tid] += t;
    __syncthreads();
  }
  if (g < N) part[g] = sm[tid];
  if (tid == 1023) bsum[blockIdx.x] = sm[1023];
}
__global__ void scan2_kernel(const int* __restrict__ bsum, int* __restrict__ bincl, int nb){
  int lane = threadIdx.x;
  int v = (lane < nb) ? bsum[lane] : 0;
  #pragma unroll
  for (int off = 1; off < 64; off <<= 1){
    int u = __shfl_up(v, off, 64);
    if (lane >= off) v += u;
  }
  if (lane < nb) bincl[lane] = v;
}
__global__ void scan3_kernel(const int* __restrict__ part, const int* __restrict__ bincl,
                             const int* __restrict__ cnt, int* __restrict__ row_start,
                             int* __restrict__ cursor, int N){
  int g = blockIdx.x*blockDim.x + threadIdx.x;
  if (g < N){
    int b = g >> 10;
    int incl = part[g] + (b ? bincl[b-1] : 0);
    int excl = incl - cnt[g];
    row_start[g] = excl;
    cursor[g]    = excl;
    if (g == N-1) row_start[N] = incl;
  }
}
__global__ void fill_kernel(const int* __restrict__ ei, int E,
                            int* __restrict__ cursor, int* __restrict__ csr){
  int e = blockIdx.x*blockDim.x + threadIdx.x;
  if (e < E){
    int dst = ei[E + e];
    int pos = atomicAdd(&cursor[dst], 1);
    csr[pos] = ei[e];  // src
  }
}

// GCN aggregation in INPUT space: thread = (node, channel-of-24). Dense lanes.
__global__ void gather24_kernel(const float* __restrict__ x, const int* __restrict__ row_start,
                                const int* __restrict__ csr, const float* __restrict__ dinv,
                                float* __restrict__ rin, int N){
  int tid = blockIdx.x*blockDim.x + threadIdx.x;
  if (tid >= N*24) return;
  int n = tid / 24;
  int c = tid - n*24;
  int s0 = row_start[n], s1 = row_start[n+1];
  float acc = 0.f;
  for (int e = s0; e < s1; ++e){
    int s = csr[e];
    acc += dinv[s] * x[s*24 + c];
  }
  float dn = dinv[n];
  rin[tid] = dn*acc + dn*dn*x[tid];
}

// Pack weights into split-bf16 B-fragment layout for mfma_f32_16x16x32_bf16.
// Logical B[k][col]: k 0-63 = s-input, 64-127 = h-input; col groups g:
//   g0=r (ih+hh), g1=z (ih+hh), g2=ni (ih only, k<64), g3=nh (hh only, k>=64)
// Frag slot q: g0: q=c4*4+kt (0-15); g1: 16+c4*4+kt; g2: 32+c4*2+kt (kt 0,1);
//   g3: 40+c4*2+(kt-2) (kt 2,3).  Within slot: lane l, el j ->
//   B[k=kt*32+(l>>4)*8+j][col=c4*16+(l&15)].  hi at q*512+l*8+j; lo at +24576.
__global__ void packB_kernel(const float* __restrict__ W_ih, const float* __restrict__ W_hh,
                             unsigned short* __restrict__ Bpk){
  int idx = blockIdx.x*blockDim.x + threadIdx.x;
  if (idx >= 48*512) return;
  int q = idx >> 9;
  int rr = idx & 511;
  int l = rr >> 3, j = rr & 7;
  int g, c4, kt;
  if (q < 32){ g = q >> 4; int rem = q & 15; c4 = rem >> 2; kt = rem & 3; }
  else if (q < 40){ g = 2; c4 = (q-32) >> 1; kt = (q-32) & 1; }
  else            { g = 3; c4 = (q-40) >> 1; kt = ((q-40) & 1) + 2; }
  int k  = kt*32 + (l >> 4)*8 + j;
  int n  = l & 15;
  int jc = c4*16 + n;
  float w;
  if (g == 0)      w = (k < 64) ? W_ih[jc*64 + k]      : W_hh[jc*64 + (k-64)];
  else if (g == 1) w = (k < 64) ? W_ih[(64+jc)*64 + k] : W_hh[(64+jc)*64 + (k-64)];
  else if (g == 2) w = W_ih[(128+jc)*64 + k];
  else             w = W_hh[(128+jc)*64 + (k-64)];
  unsigned short hi = f2bf(w);
  unsigned short lo = f2bf(w - bf2f(hi));
  Bpk[q*512 + l*8 + j]         = hi;
  Bpk[24576 + q*512 + l*8 + j] = lo;
}

// Fused 12-step GRU + FC via split-bf16 MFMA. Wave = 16 nodes.
// Weights (96 KB, hi+lo B-frags) block-resident in LDS. Per-wave X tile
// [16 x 128] fp32 in LDS holds [s | h]; h also lives in C-layout registers.
// 1 block/CU (LDS 155 KB) -> VGPRs unconstrained (waves_per_eu(1,1)).
__global__ __attribute__((amdgpu_waves_per_eu(1, 1))) __launch_bounds__(GBLOCK)
void gru_mfma_kernel(const float* __restrict__ rin,
                     const float* __restrict__ W_gcn, const float* __restrict__ b_gcn,
                     const unsigned short* __restrict__ Bpk,
                     const float* __restrict__ b_ih, const float* __restrict__ b_hh,
                     const float* __restrict__ W_fc, const float* __restrict__ b_fc,
                     float* __restrict__ out, int N){
  extern __shared__ char smem[];
  short* Bl = (short*)smem;
  float* Xl = (float*)(smem + B_LDS_BYTES);
  float* rl = (float*)(smem + B_LDS_BYTES + X_LDS_BYTES);

  // stage B-frags (98304 B = 6144 int4) and this block's rin rows
  {
    const int4* Bg = (const int4*)Bpk;
    int4* Bd = (int4*)smem;
    for (int i = threadIdx.x; i < 6144; i += GBLOCK) Bd[i] = Bg[i];
    int nb = blockIdx.x * (GWPB*16);
    for (int i = threadIdx.x; i < GWPB*16*24; i += GBLOCK){
      int g = nb*24 + i;
      rl[i] = (g < N*24) ? rin[g] : 0.f;
    }
  }
  __syncthreads();

  int lane = threadIdx.x & 63;
  int wid  = threadIdx.x >> 6;
  int tile = blockIdx.x*GWPB + wid;
  int ntiles = (N + 15) >> 4;
  if (tile >= ntiles) return;
  int n0   = tile << 4;
  int quad = lane >> 4;
  int n16  = lane & 15;
  float* Xw = Xl + wid*XWSZ;

  float wg0 = W_gcn[lane], wg1 = W_gcn[HID+lane], bg = b_gcn[lane];
  float wfc = W_fc[lane],  bfc = b_fc[0];
  float bR[4], bZ[4], bNi[4], bNh[4];
  #pragma unroll
  for (int c4 = 0; c4 < 4; ++c4){
    int jc = c4*16 + n16;
    bR[c4]  = b_ih[jc]      + b_hh[jc];
    bZ[c4]  = b_ih[64+jc]   + b_hh[64+jc];
    bNi[c4] = b_ih[128+jc];
    bNh[c4] = b_hh[128+jc];
  }

  // h := 0 (LDS copy + C-layout registers)
  #pragma unroll
  for (int m = 0; m < 16; ++m) Xw[m*XSTRIDE + 64 + lane] = 0.f;
  floatx4 hreg[4];
  #pragma unroll
  for (int c4 = 0; c4 < 4; ++c4) hreg[c4] = (floatx4){0.f,0.f,0.f,0.f};

  #pragma unroll 1
  for (int t = 0; t < T_STEPS; ++t){
    // s phase: s[m][ch=lane] = relu(rin @ W_gcn + b_gcn), write to X k=0..63
    #pragma unroll
    for (int m = 0; m < 16; ++m){
      const float* rp = &rl[(wid*16 + m)*24 + 2*t];
      float r0 = rp[0], r1 = rp[1];                  // wave-uniform broadcast
      Xw[m*XSTRIDE + lane] = fmaxf(fmaf(r0, wg0, fmaf(r1, wg1, bg)), 0.f);
    }

    // A-fragments: X[m=n16][k=kt*32+quad*8+j], split hi/lo bf16
    short8 ahi[4], alo[4];
    #pragma unroll
    for (int kt = 0; kt < 4; ++kt){
      int base = n16*XSTRIDE + kt*32 + quad*8;
      floatx4 xa = *(floatx4*)&Xw[base];
      floatx4 xb = *(floatx4*)&Xw[base+4];
      float xs[8] = {xa[0],xa[1],xa[2],xa[3],xb[0],xb[1],xb[2],xb[3]};
      short8 h8, l8;
      #pragma unroll
      for (int j = 0; j < 8; ++j){
        unsigned short h = f2bf(xs[j]);
        h8[j] = (short)h;
        l8[j] = (short)f2bf(xs[j] - bf2f(h));
      }
      ahi[kt] = h8; alo[kt] = l8;
    }

    // gates + GRU update, one 16-channel group (c4) at a time
    #pragma unroll
    for (int c4 = 0; c4 < 4; ++c4){
      floatx4 aR  = (floatx4){bR[c4], bR[c4], bR[c4], bR[c4]};
      floatx4 aZ  = (floatx4){bZ[c4], bZ[c4], bZ[c4], bZ[c4]};
      floatx4 aNi = (floatx4){bNi[c4],bNi[c4],bNi[c4],bNi[c4]};
      floatx4 aNh = (floatx4){bNh[c4],bNh[c4],bNh[c4],bNh[c4]};
      #pragma unroll
      for (int kt = 0; kt < 4; ++kt){
        int qr = (c4<<2) + kt;
        short8 wh = *(short8*)&Bl[qr*512 + lane*8];
        short8 wl = *(short8*)&Bl[24576 + qr*512 + lane*8];
        aR = __builtin_amdgcn_mfma_f32_16x16x32_bf16(ahi[kt], wh, aR, 0,0,0);
        aR = __builtin_amdgcn_mfma_f32_16x16x32_bf16(alo[kt], wh, aR, 0,0,0);
        aR = __builtin_amdgcn_mfma_f32_16x16x32_bf16(ahi[kt], wl, aR, 0,0,0);
        int qz = 16 + (c4<<2) + kt;
        wh = *(short8*)&Bl[qz*512 + lane*8];
        wl = *(short8*)&Bl[24576 + qz*512 + lane*8];
        aZ = __builtin_amdgcn_mfma_f32_16x16x32_bf16(ahi[kt], wh, aZ, 0,0,0);
        aZ = __builtin_amdgcn_mfma_f32_16x16x32_bf16(alo[kt], wh, aZ, 0,0,0);
        aZ = __builtin_amdgcn_mfma_f32_16x16x32_bf16(ahi[kt], wl, aZ, 0,0,0);
        if (kt < 2){
          int qn = 32 + (c4<<1) + kt;
          wh = *(short8*)&Bl[qn*512 + lane*8];
          wl = *(short8*)&Bl[24576 + qn*512 + lane*8];
          aNi = __builtin_amdgcn_mfma_f32_16x16x32_bf16(ahi[kt], wh, aNi, 0,0,0);
          aNi = __builtin_amdgcn_mfma_f32_16x16x32_bf16(alo[kt], wh, aNi, 0,0,0);
          aNi = __builtin_amdgcn_mfma_f32_16x16x32_bf16(ahi[kt], wl, aNi, 0,0,0);
        } else {
          int qn = 40 + (c4<<1) + (kt-2);
          wh = *(short8*)&Bl[qn*512 + lane*8];
          wl = *(short8*)&Bl[24576 + qn*512 + lane*8];
          aNh = __builtin_amdgcn_mfma_f32_16x16x32_bf16(ahi[kt], wh, aNh, 0,0,0);
          aNh = __builtin_amdgcn_mfma_f32_16x16x32_bf16(alo[kt], wh, aNh, 0,0,0);
          aNh = __builtin_amdgcn_mfma_f32_16x16x32_bf16(ahi[kt], wl, aNh, 0,0,0);
        }
      }
      // epilogue: C/D layout row = quad*4+r, col = c4*16+n16
      #pragma unroll
      for (int r = 0; r < 4; ++r){
        float rg = sigmoidf_(aR[r]);
        float zg = sigmoidf_(aZ[r]);
        float ng = tanhf_(aNi[r] + rg*aNh[r]);
        float hn = (1.f - zg)*ng + zg*hreg[c4][r];
        hreg[c4][r] = hn;
        Xw[(quad*4 + r)*XSTRIDE + 64 + c4*16 + n16] = hn;
      }
    }
  }

  // FC epilogue: out[n] = dot(h[n], W_fc) + b_fc
  #pragma unroll 1
  for (int m = 0; m < 16; ++m){
    float v = Xw[m*XSTRIDE + 64 + lane] * wfc;
    #pragma unroll
    for (int off = 32; off >= 1; off >>= 1) v += __shfl_xor(v, off, 64);
    int n = n0 + m;
    if (lane == 0 && n < N) out[n] = v + bfc;
  }
}

extern "C" void kernel_launch(void* const* d_in, const int* in_sizes, int n_in,
                              void* d_out, int out_size, void* d_ws, size_t ws_size,
                              hipStream_t stream){
  const float* x     = (const float*)d_in[0];
  const int*   ei    = (const int*)d_in[1];
  const float* W_gcn = (const float*)d_in[2];
  const float* b_gcn = (const float*)d_in[3];
  const float* W_ih  = (const float*)d_in[4];
  const float* W_hh  = (const float*)d_in[5];
  const float* b_ih  = (const float*)d_in[6];
  const float* b_hh  = (const float*)d_in[7];
  const float* W_fc  = (const float*)d_in[8];
  const float* b_fc  = (const float*)d_in[9];
  float* out = (float*)d_out;
  const int N = in_sizes[0] / (T_STEPS*2);
  const int E = in_sizes[1] / 2;
  const int NB1024 = (N + 1023) / 1024;

  char* p = (char*)d_ws;
  auto alloc = [&](size_t bytes)->char*{
    char* r = p; p += (bytes + 255) & ~(size_t)255; return r;
  };
  int*   cnt       = (int*)  alloc((size_t)N*4);
  int*   row_start = (int*)  alloc((size_t)(N+1)*4);
  int*   cursor    = (int*)  alloc((size_t)N*4);
  int*   csr       = (int*)  alloc((size_t)E*4);
  float* dinv      = (float*)alloc((size_t)N*4);
  int*   part      = (int*)  alloc((size_t)N*4);
  int*   bsum      = (int*)  alloc((size_t)NB1024*4);
  int*   bincl     = (int*)  alloc((size_t)NB1024*4);
  float* rin       = (float*)alloc((size_t)N*24*4);
  unsigned short* Bpk = (unsigned short*)alloc((size_t)49152*2);

  hipMemsetAsync(cnt, 0, (size_t)N*4, stream);
  count_kernel<<<(E+255)/256, 256, 0, stream>>>(ei, E, cnt);
  dinv_kernel<<<(N+255)/256, 256, 0, stream>>>(cnt, dinv, N);
  scan1_kernel<<<NB1024, 1024, 0, stream>>>(cnt, part, bsum, N);
  scan2_kernel<<<1, 64, 0, stream>>>(bsum, bincl, NB1024);
  scan3_kernel<<<(N+255)/256, 256, 0, stream>>>(part, bincl, cnt, row_start, cursor, N);
  fill_kernel<<<(E+255)/256, 256, 0, stream>>>(ei, E, cursor, csr);
  packB_kernel<<<(48*512+255)/256, 256, 0, stream>>>(W_ih, W_hh, Bpk);
  gather24_kernel<<<(N*24+255)/256, 256, 0, stream>>>(x, row_start, csr, dinv, rin, N);

  // allow >64 KB dynamic LDS (no-op if unnecessary; safe under graph capture)
  (void)hipFuncSetAttribute((const void*)gru_mfma_kernel,
                            hipFuncAttributeMaxDynamicSharedMemorySize, LDS_TOTAL);
  int ntiles = (N + 15) / 16;
  int blocks = (ntiles + GWPB - 1) / GWPB;
  gru_mfma_kernel<<<blocks, GBLOCK, LDS_TOTAL, stream>>>(rin, W_gcn, b_gcn, Bpk,
                                                         b_ih, b_hh, W_fc, b_fc, out, N);
}

// Round 7
// 422.127 us; speedup vs baseline: 2.7682x; 1.1297x over previous
//
#include <hip/hip_runtime.h>
#include <math.h>

#define T_STEPS 12
#define HID 64
#define GWPB 12             // waves per block
#define GBLOCK (GWPB*64)    // 768 threads
#define HSTR 68             // h-tile row stride (fp32): 16B-aligned rows, bank-spread
#define B_LDS_BYTES 98304   // 48 frag-slots x 1KB x {hi,lo}
#define H_LDS_BYTES (GWPB*16*HSTR*4)        // 52224
#define WG_LDS_BYTES 768                    // wg0|wg1|bg (64 fp32 each)
#define LDS_TOTAL (B_LDS_BYTES + H_LDS_BYTES + WG_LDS_BYTES)  // 151296 <= 160 KiB

typedef __attribute__((ext_vector_type(8))) short short8;
typedef __attribute__((ext_vector_type(4))) float floatx4;

__device__ __forceinline__ float sigmoidf_(float x){ return 1.0f/(1.0f + __expf(-x)); }
__device__ __forceinline__ float tanhf_(float x){
  float e = __expf(-2.0f * fabsf(x));
  float t = (1.0f - e) / (1.0f + e);
  return copysignf(t, x);
}
__device__ __forceinline__ unsigned short f2bf(float x){
  unsigned int u = __float_as_uint(x);
  unsigned int r = (u + 0x7FFFu + ((u >> 16) & 1u)) >> 16;  // RNE
  return (unsigned short)r;
}
__device__ __forceinline__ float bf2f(unsigned short h){
  return __uint_as_float(((unsigned int)h) << 16);
}

// --- CSR build ----------------------------------------------------------
__global__ void count_kernel(const int* __restrict__ ei, int E, int* __restrict__ cnt){
  int e = blockIdx.x*blockDim.x + threadIdx.x;
  if (e < E) atomicAdd(&cnt[ei[E + e]], 1);
}
__global__ void dinv_kernel(const int* __restrict__ cnt, float* __restrict__ dinv, int N){
  int i = blockIdx.x*blockDim.x + threadIdx.x;
  if (i < N) dinv[i] = 1.0f / sqrtf((float)cnt[i] + 1.0f);
}
__global__ void scan1_kernel(const int* __restrict__ cnt, int* __restrict__ part,
                             int* __restrict__ bsum, int N){
  __shared__ int sm[1024];
  int tid = threadIdx.x;
  int g = blockIdx.x*1024 + tid;
  int v = (g < N) ? cnt[g] : 0;
  sm[tid] = v; __syncthreads();
  for (int off = 1; off < 1024; off <<= 1){
    int t = (tid >= off) ? sm[tid-off] : 0;
    __syncthreads();
    sm[tid] += t;
    __syncthreads();
  }
  if (g < N) part[g] = sm[tid];
  if (tid == 1023) bsum[blockIdx.x] = sm[1023];
}
__global__ void scan2_kernel(const int* __restrict__ bsum, int* __restrict__ bincl, int nb){
  int lane = threadIdx.x;
  int v = (lane < nb) ? bsum[lane] : 0;
  #pragma unroll
  for (int off = 1; off < 64; off <<= 1){
    int u = __shfl_up(v, off, 64);
    if (lane >= off) v += u;
  }
  if (lane < nb) bincl[lane] = v;
}
__global__ void scan3_kernel(const int* __restrict__ part, const int* __restrict__ bincl,
                             const int* __restrict__ cnt, int* __restrict__ row_start,
                             int* __restrict__ cursor, int N){
  int g = blockIdx.x*blockDim.x + threadIdx.x;
  if (g < N){
    int b = g >> 10;
    int incl = part[g] + (b ? bincl[b-1] : 0);
    int excl = incl - cnt[g];
    row_start[g] = excl;
    cursor[g]    = excl;
    if (g == N-1) row_start[N] = incl;
  }
}
__global__ void fill_kernel(const int* __restrict__ ei, int E,
                            int* __restrict__ cursor, int* __restrict__ csr){
  int e = blockIdx.x*blockDim.x + threadIdx.x;
  if (e < E){
    int dst = ei[E + e];
    int pos = atomicAdd(&cursor[dst], 1);
    csr[pos] = ei[e];  // src
  }
}

// GCN aggregation in INPUT space. Thread = (node, float4-chunk of 24ch row).
// float4 loads cut inner-loop trips 4x vs gather24; 2-way unroll for latency.
__global__ void gather6_kernel(const float* __restrict__ x, const int* __restrict__ row_start,
                               const int* __restrict__ csr, const float* __restrict__ dinv,
                               float* __restrict__ rin, int N){
  int tid = blockIdx.x*blockDim.x + threadIdx.x;
  if (tid >= N*6) return;
  int n = tid / 6;
  int q = tid - n*6;
  int s0 = row_start[n], s1 = row_start[n+1];
  const float4* x4 = (const float4*)x;
  float4 acc = make_float4(0.f,0.f,0.f,0.f);
  int e = s0;
  for (; e + 1 < s1; e += 2){
    int sa = csr[e],   sb = csr[e+1];
    float da = dinv[sa], db = dinv[sb];
    float4 va = x4[sa*6 + q];
    float4 vb = x4[sb*6 + q];
    acc.x += da*va.x + db*vb.x;
    acc.y += da*va.y + db*vb.y;
    acc.z += da*va.z + db*vb.z;
    acc.w += da*va.w + db*vb.w;
  }
  if (e < s1){
    int sa = csr[e];
    float da = dinv[sa];
    float4 va = x4[sa*6 + q];
    acc.x += da*va.x; acc.y += da*va.y; acc.z += da*va.z; acc.w += da*va.w;
  }
  float dn = dinv[n];
  float dn2 = dn*dn;
  float4 self = x4[n*6 + q];
  float4 r;
  r.x = dn*acc.x + dn2*self.x;
  r.y = dn*acc.y + dn2*self.y;
  r.z = dn*acc.z + dn2*self.z;
  r.w = dn*acc.w + dn2*self.w;
  ((float4*)rin)[tid] = r;
}

// Pack weights into split-bf16 B-fragment layout for mfma_f32_16x16x32_bf16
// (identical to round-6 proven layout).
__global__ void packB_kernel(const float* __restrict__ W_ih, const float* __restrict__ W_hh,
                             unsigned short* __restrict__ Bpk){
  int idx = blockIdx.x*blockDim.x + threadIdx.x;
  if (idx >= 48*512) return;
  int q = idx >> 9;
  int rr = idx & 511;
  int l = rr >> 3, j = rr & 7;
  int g, c4, kt;
  if (q < 32){ g = q >> 4; int rem = q & 15; c4 = rem >> 2; kt = rem & 3; }
  else if (q < 40){ g = 2; c4 = (q-32) >> 1; kt = (q-32) & 1; }
  else            { g = 3; c4 = (q-40) >> 1; kt = ((q-40) & 1) + 2; }
  int k  = kt*32 + (l >> 4)*8 + j;
  int n  = l & 15;
  int jc = c4*16 + n;
  float w;
  if (g == 0)      w = (k < 64) ? W_ih[jc*64 + k]      : W_hh[jc*64 + (k-64)];
  else if (g == 1) w = (k < 64) ? W_ih[(64+jc)*64 + k] : W_hh[(64+jc)*64 + (k-64)];
  else if (g == 2) w = W_ih[(128+jc)*64 + k];
  else             w = W_hh[(128+jc)*64 + (k-64)];
  unsigned short hi = f2bf(w);
  unsigned short lo = f2bf(w - bf2f(hi));
  Bpk[q*512 + l*8 + j]         = hi;
  Bpk[24576 + q*512 + l*8 + j] = lo;
}

// Fused 12-step GRU + FC via split-bf16 MFMA. Wave = 16 nodes.
// s computed DIRECTLY in A-fragment layout (no transpose, no m-loop):
//   lane(quad,n16) owns s[m=n16][k=kt*32+quad*8+j].
// h transposed C->A through a per-wave 16xHSTR LDS tile (b128-aligned rows).
// rin streamed from global (8 B/lane/t) with 1-step-ahead prefetch.
__global__ __attribute__((amdgpu_waves_per_eu(1, 3))) __launch_bounds__(GBLOCK)
void gru_mfma_kernel(const float* __restrict__ rin,
                     const float* __restrict__ W_gcn, const float* __restrict__ b_gcn,
                     const unsigned short* __restrict__ Bpk,
                     const float* __restrict__ b_ih, const float* __restrict__ b_hh,
                     const float* __restrict__ W_fc, const float* __restrict__ b_fc,
                     float* __restrict__ out, int N){
  extern __shared__ char smem[];
  short* Bl  = (short*)smem;
  float* hl  = (float*)(smem + B_LDS_BYTES);
  float* wgl = (float*)(smem + B_LDS_BYTES + H_LDS_BYTES);

  // stage B-frags (96 KB) + wg (768 B)
  {
    const int4* Bg = (const int4*)Bpk;
    int4* Bd = (int4*)smem;
    #pragma unroll
    for (int i = 0; i < 6144/GBLOCK; ++i)
      Bd[i*GBLOCK + threadIdx.x] = Bg[i*GBLOCK + threadIdx.x];
    if (threadIdx.x < 64){
      wgl[threadIdx.x]       = W_gcn[threadIdx.x];        // wg0[j]
      wgl[64 + threadIdx.x]  = W_gcn[64 + threadIdx.x];   // wg1[j]
      wgl[128 + threadIdx.x] = b_gcn[threadIdx.x];        // bg[j]
    }
  }
  __syncthreads();

  int lane = threadIdx.x & 63;
  int wid  = threadIdx.x >> 6;
  int tile = blockIdx.x*GWPB + wid;
  int ntiles = (N + 15) >> 4;
  if (tile >= ntiles) return;
  int n0   = tile << 4;
  int quad = lane >> 4;
  int n16  = lane & 15;
  float* hw = hl + wid*(16*HSTR);

  // zero h-tile (per-wave region; wave-coherent, no barrier needed)
  for (int i = lane; i < 16*HSTR; i += 64) hw[i] = 0.f;

  float wfc = W_fc[lane], bfc = b_fc[0];
  float bR[4], bZ[4], bNi[4], bNh[4];
  #pragma unroll
  for (int c4 = 0; c4 < 4; ++c4){
    int jc = c4*16 + n16;
    bR[c4]  = b_ih[jc]      + b_hh[jc];
    bZ[c4]  = b_ih[64+jc]   + b_hh[64+jc];
    bNi[c4] = b_ih[128+jc];
    bNh[c4] = b_hh[128+jc];
  }

  floatx4 hreg[4];
  #pragma unroll
  for (int c4 = 0; c4 < 4; ++c4) hreg[c4] = (floatx4){0.f,0.f,0.f,0.f};

  int nn = (n0 + n16 < N) ? (n0 + n16) : (N-1);
  const float* rbase = rin + (size_t)nn*24;
  float2 rcur = *(const float2*)rbase;   // t=0

  #pragma unroll 1
  for (int t = 0; t < T_STEPS; ++t){
    // prefetch next t's rin pair (consumed next iteration)
    float2 rnx = (t < T_STEPS-1) ? *(const float2*)(rbase + 2*(t+1)) : rcur;
    float r0 = rcur.x, r1 = rcur.y;

    // A-fragments, split hi/lo bf16
    short8 ahi[4], alo[4];
    #pragma unroll
    for (int kt = 0; kt < 2; ++kt){        // s half: compute in-place
      int j0 = kt*32 + quad*8;
      floatx4 g0a = *(floatx4*)&wgl[j0],       g0b = *(floatx4*)&wgl[j0+4];
      floatx4 g1a = *(floatx4*)&wgl[64 + j0],  g1b = *(floatx4*)&wgl[64 + j0+4];
      floatx4 bga = *(floatx4*)&wgl[128 + j0], bgb = *(floatx4*)&wgl[128 + j0+4];
      short8 h8, l8;
      #pragma unroll
      for (int j = 0; j < 4; ++j){
        float sv = fmaxf(fmaf(r0, g0a[j], fmaf(r1, g1a[j], bga[j])), 0.f);
        unsigned short hh = f2bf(sv);
        h8[j] = (short)hh; l8[j] = (short)f2bf(sv - bf2f(hh));
        float sw = fmaxf(fmaf(r0, g0b[j], fmaf(r1, g1b[j], bgb[j])), 0.f);
        unsigned short hw2 = f2bf(sw);
        h8[4+j] = (short)hw2; l8[4+j] = (short)f2bf(sw - bf2f(hw2));
      }
      ahi[kt] = h8; alo[kt] = l8;
    }
    #pragma unroll
    for (int kt = 2; kt < 4; ++kt){        // h half: from LDS tile
      int base = n16*HSTR + (kt-2)*32 + quad*8;
      floatx4 xa = *(floatx4*)&hw[base];
      floatx4 xb = *(floatx4*)&hw[base+4];
      short8 h8, l8;
      #pragma unroll
      for (int j = 0; j < 4; ++j){
        unsigned short ha = f2bf(xa[j]);
        h8[j] = (short)ha; l8[j] = (short)f2bf(xa[j] - bf2f(ha));
        unsigned short hb = f2bf(xb[j]);
        h8[4+j] = (short)hb; l8[4+j] = (short)f2bf(xb[j] - bf2f(hb));
      }
      ahi[kt] = h8; alo[kt] = l8;
    }

    // gates + GRU update, one 16-channel group (c4) at a time
    #pragma unroll
    for (int c4 = 0; c4 < 4; ++c4){
      floatx4 aR  = (floatx4){bR[c4], bR[c4], bR[c4], bR[c4]};
      floatx4 aZ  = (floatx4){bZ[c4], bZ[c4], bZ[c4], bZ[c4]};
      floatx4 aNi = (floatx4){bNi[c4],bNi[c4],bNi[c4],bNi[c4]};
      floatx4 aNh = (floatx4){bNh[c4],bNh[c4],bNh[c4],bNh[c4]};
      #pragma unroll
      for (int kt = 0; kt < 4; ++kt){
        int qr = (c4<<2) + kt;
        short8 wh = *(short8*)&Bl[qr*512 + lane*8];
        short8 wl = *(short8*)&Bl[24576 + qr*512 + lane*8];
        aR = __builtin_amdgcn_mfma_f32_16x16x32_bf16(ahi[kt], wh, aR, 0,0,0);
        aR = __builtin_amdgcn_mfma_f32_16x16x32_bf16(alo[kt], wh, aR, 0,0,0);
        aR = __builtin_amdgcn_mfma_f32_16x16x32_bf16(ahi[kt], wl, aR, 0,0,0);
        int qz = 16 + (c4<<2) + kt;
        wh = *(short8*)&Bl[qz*512 + lane*8];
        wl = *(short8*)&Bl[24576 + qz*512 + lane*8];
        aZ = __builtin_amdgcn_mfma_f32_16x16x32_bf16(ahi[kt], wh, aZ, 0,0,0);
        aZ = __builtin_amdgcn_mfma_f32_16x16x32_bf16(alo[kt], wh, aZ, 0,0,0);
        aZ = __builtin_amdgcn_mfma_f32_16x16x32_bf16(ahi[kt], wl, aZ, 0,0,0);
        if (kt < 2){
          int qn = 32 + (c4<<1) + kt;
          wh = *(short8*)&Bl[qn*512 + lane*8];
          wl = *(short8*)&Bl[24576 + qn*512 + lane*8];
          aNi = __builtin_amdgcn_mfma_f32_16x16x32_bf16(ahi[kt], wh, aNi, 0,0,0);
          aNi = __builtin_amdgcn_mfma_f32_16x16x32_bf16(alo[kt], wh, aNi, 0,0,0);
          aNi = __builtin_amdgcn_mfma_f32_16x16x32_bf16(ahi[kt], wl, aNi, 0,0,0);
        } else {
          int qn = 40 + (c4<<1) + (kt-2);
          wh = *(short8*)&Bl[qn*512 + lane*8];
          wl = *(short8*)&Bl[24576 + qn*512 + lane*8];
          aNh = __builtin_amdgcn_mfma_f32_16x16x32_bf16(ahi[kt], wh, aNh, 0,0,0);
          aNh = __builtin_amdgcn_mfma_f32_16x16x32_bf16(alo[kt], wh, aNh, 0,0,0);
          aNh = __builtin_amdgcn_mfma_f32_16x16x32_bf16(ahi[kt], wl, aNh, 0,0,0);
        }
      }
      // epilogue: C/D layout row = quad*4+r, col = c4*16+n16
      #pragma unroll
      for (int r = 0; r < 4; ++r){
        float rg = sigmoidf_(aR[r]);
        float zg = sigmoidf_(aZ[r]);
        float ng = tanhf_(aNi[r] + rg*aNh[r]);
        float hn = (1.f - zg)*ng + zg*hreg[c4][r];
        hreg[c4][r] = hn;
        hw[(quad*4 + r)*HSTR + c4*16 + n16] = hn;
      }
    }
    rcur = rnx;
  }

  // FC epilogue: out[n] = dot(h[n], W_fc) + b_fc  (h rows are in hw)
  #pragma unroll 1
  for (int m = 0; m < 16; ++m){
    float v = hw[m*HSTR + lane] * wfc;
    #pragma unroll
    for (int off = 32; off >= 1; off >>= 1) v += __shfl_xor(v, off, 64);
    int n = n0 + m;
    if (lane == 0 && n < N) out[n] = v + bfc;
  }
}

extern "C" void kernel_launch(void* const* d_in, const int* in_sizes, int n_in,
                              void* d_out, int out_size, void* d_ws, size_t ws_size,
                              hipStream_t stream){
  const float* x     = (const float*)d_in[0];
  const int*   ei    = (const int*)d_in[1];
  const float* W_gcn = (const float*)d_in[2];
  const float* b_gcn = (const float*)d_in[3];
  const float* W_ih  = (const float*)d_in[4];
  const float* W_hh  = (const float*)d_in[5];
  const float* b_ih  = (const float*)d_in[6];
  const float* b_hh  = (const float*)d_in[7];
  const float* W_fc  = (const float*)d_in[8];
  const float* b_fc  = (const float*)d_in[9];
  float* out = (float*)d_out;
  const int N = in_sizes[0] / (T_STEPS*2);
  const int E = in_sizes[1] / 2;
  const int NB1024 = (N + 1023) / 1024;

  char* p = (char*)d_ws;
  auto alloc = [&](size_t bytes)->char*{
    char* r = p; p += (bytes + 255) & ~(size_t)255; return r;
  };
  int*   cnt       = (int*)  alloc((size_t)N*4);
  int*   row_start = (int*)  alloc((size_t)(N+1)*4);
  int*   cursor    = (int*)  alloc((size_t)N*4);
  int*   csr       = (int*)  alloc((size_t)E*4);
  float* dinv      = (float*)alloc((size_t)N*4);
  int*   part      = (int*)  alloc((size_t)N*4);
  int*   bsum      = (int*)  alloc((size_t)NB1024*4);
  int*   bincl     = (int*)  alloc((size_t)NB1024*4);
  float* rin       = (float*)alloc((size_t)N*24*4);
  unsigned short* Bpk = (unsigned short*)alloc((size_t)49152*2);

  hipMemsetAsync(cnt, 0, (size_t)N*4, stream);
  count_kernel<<<(E+255)/256, 256, 0, stream>>>(ei, E, cnt);
  dinv_kernel<<<(N+255)/256, 256, 0, stream>>>(cnt, dinv, N);
  scan1_kernel<<<NB1024, 1024, 0, stream>>>(cnt, part, bsum, N);
  scan2_kernel<<<1, 64, 0, stream>>>(bsum, bincl, NB1024);
  scan3_kernel<<<(N+255)/256, 256, 0, stream>>>(part, bincl, cnt, row_start, cursor, N);
  fill_kernel<<<(E+255)/256, 256, 0, stream>>>(ei, E, cursor, csr);
  packB_kernel<<<(48*512+255)/256, 256, 0, stream>>>(W_ih, W_hh, Bpk);
  gather6_kernel<<<(N*6+255)/256, 256, 0, stream>>>(x, row_start, csr, dinv, rin, N);

  (void)hipFuncSetAttribute((const void*)gru_mfma_kernel,
                            hipFuncAttributeMaxDynamicSharedMemorySize, LDS_TOTAL);
  int ntiles = (N + 15) / 16;
  int blocks = (ntiles + GWPB - 1) / GWPB;
  gru_mfma_kernel<<<blocks, GBLOCK, LDS_TOTAL, stream>>>(rin, W_gcn, b_gcn, Bpk,
                                                         b_ih, b_hh, W_fc, b_fc, out, N);
}

// Round 8
// 367.937 us; speedup vs baseline: 3.1759x; 1.1473x over previous
//
#include <hip/hip_runtime.h>
#include <math.h>

#define T_STEPS 12
#define HID 64
#define GWPB 7              // waves per block (1 block/CU, 224 blocks total)
#define GBLOCK (GWPB*64)    // 448 threads
#define HSTR 68             // h-tile row stride (fp32): 16B-aligned rows, bank-spread
#define B_LDS_BYTES 98304   // 48 frag-slots x 1KB x {hi,lo}
#define H_LDS_BYTES (GWPB*32*HSTR*4)        // 60928 (32 rows per wave now)
#define WG_LDS_BYTES 768                    // wg0|wg1|bg (64 fp32 each)
#define LDS_TOTAL (B_LDS_BYTES + H_LDS_BYTES + WG_LDS_BYTES)  // 160000 <= 163840

typedef __attribute__((ext_vector_type(8))) short short8;
typedef __attribute__((ext_vector_type(4))) float floatx4;

__device__ __forceinline__ float sigmoidf_(float x){ return 1.0f/(1.0f + __expf(-x)); }
__device__ __forceinline__ float tanhf_(float x){
  float e = __expf(-2.0f * fabsf(x));
  float t = (1.0f - e) / (1.0f + e);
  return copysignf(t, x);
}
__device__ __forceinline__ unsigned short f2bf(float x){
  unsigned int u = __float_as_uint(x);
  unsigned int r = (u + 0x7FFFu + ((u >> 16) & 1u)) >> 16;  // RNE
  return (unsigned short)r;
}
__device__ __forceinline__ float bf2f(unsigned short h){
  return __uint_as_float(((unsigned int)h) << 16);
}

// --- CSR build ----------------------------------------------------------
__global__ void count_kernel(const int* __restrict__ ei, int E, int* __restrict__ cnt){
  int e = blockIdx.x*blockDim.x + threadIdx.x;
  if (e < E) atomicAdd(&cnt[ei[E + e]], 1);
}
__global__ void dinv_kernel(const int* __restrict__ cnt, float* __restrict__ dinv, int N){
  int i = blockIdx.x*blockDim.x + threadIdx.x;
  if (i < N) dinv[i] = 1.0f / sqrtf((float)cnt[i] + 1.0f);
}
__global__ void scan1_kernel(const int* __restrict__ cnt, int* __restrict__ part,
                             int* __restrict__ bsum, int N){
  __shared__ int sm[1024];
  int tid = threadIdx.x;
  int g = blockIdx.x*1024 + tid;
  int v = (g < N) ? cnt[g] : 0;
  sm[tid] = v; __syncthreads();
  for (int off = 1; off < 1024; off <<= 1){
    int t = (tid >= off) ? sm[tid-off] : 0;
    __syncthreads();
    sm[tid] += t;
    __syncthreads();
  }
  if (g < N) part[g] = sm[tid];
  if (tid == 1023) bsum[blockIdx.x] = sm[1023];
}
__global__ void scan2_kernel(const int* __restrict__ bsum, int* __restrict__ bincl, int nb){
  int lane = threadIdx.x;
  int v = (lane < nb) ? bsum[lane] : 0;
  #pragma unroll
  for (int off = 1; off < 64; off <<= 1){
    int u = __shfl_up(v, off, 64);
    if (lane >= off) v += u;
  }
  if (lane < nb) bincl[lane] = v;
}
__global__ void scan3_kernel(const int* __restrict__ part, const int* __restrict__ bincl,
                             const int* __restrict__ cnt, int* __restrict__ row_start,
                             int* __restrict__ cursor, int N){
  int g = blockIdx.x*blockDim.x + threadIdx.x;
  if (g < N){
    int b = g >> 10;
    int incl = part[g] + (b ? bincl[b-1] : 0);
    int excl = incl - cnt[g];
    row_start[g] = excl;
    cursor[g]    = excl;
    if (g == N-1) row_start[N] = incl;
  }
}
__global__ void fill_kernel(const int* __restrict__ ei, int E,
                            int* __restrict__ cursor, int* __restrict__ csr){
  int e = blockIdx.x*blockDim.x + threadIdx.x;
  if (e < E){
    int dst = ei[E + e];
    int pos = atomicAdd(&cursor[dst], 1);
    csr[pos] = ei[e];  // src
  }
}

// GCN aggregation in INPUT space. Thread = (node, float4-chunk of 24ch row).
__global__ void gather6_kernel(const float* __restrict__ x, const int* __restrict__ row_start,
                               const int* __restrict__ csr, const float* __restrict__ dinv,
                               float* __restrict__ rin, int N){
  int tid = blockIdx.x*blockDim.x + threadIdx.x;
  if (tid >= N*6) return;
  int n = tid / 6;
  int q = tid - n*6;
  int s0 = row_start[n], s1 = row_start[n+1];
  const float4* x4 = (const float4*)x;
  float4 acc = make_float4(0.f,0.f,0.f,0.f);
  int e = s0;
  for (; e + 1 < s1; e += 2){
    int sa = csr[e],   sb = csr[e+1];
    float da = dinv[sa], db = dinv[sb];
    float4 va = x4[sa*6 + q];
    float4 vb = x4[sb*6 + q];
    acc.x += da*va.x + db*vb.x;
    acc.y += da*va.y + db*vb.y;
    acc.z += da*va.z + db*vb.z;
    acc.w += da*va.w + db*vb.w;
  }
  if (e < s1){
    int sa = csr[e];
    float da = dinv[sa];
    float4 va = x4[sa*6 + q];
    acc.x += da*va.x; acc.y += da*va.y; acc.z += da*va.z; acc.w += da*va.w;
  }
  float dn = dinv[n];
  float dn2 = dn*dn;
  float4 self = x4[n*6 + q];
  float4 r;
  r.x = dn*acc.x + dn2*self.x;
  r.y = dn*acc.y + dn2*self.y;
  r.z = dn*acc.z + dn2*self.z;
  r.w = dn*acc.w + dn2*self.w;
  ((float4*)rin)[tid] = r;
}

// Pack weights into split-bf16 B-fragment layout (round-6 proven layout).
__global__ void packB_kernel(const float* __restrict__ W_ih, const float* __restrict__ W_hh,
                             unsigned short* __restrict__ Bpk){
  int idx = blockIdx.x*blockDim.x + threadIdx.x;
  if (idx >= 48*512) return;
  int q = idx >> 9;
  int rr = idx & 511;
  int l = rr >> 3, j = rr & 7;
  int g, c4, kt;
  if (q < 32){ g = q >> 4; int rem = q & 15; c4 = rem >> 2; kt = rem & 3; }
  else if (q < 40){ g = 2; c4 = (q-32) >> 1; kt = (q-32) & 1; }
  else            { g = 3; c4 = (q-40) >> 1; kt = ((q-40) & 1) + 2; }
  int k  = kt*32 + (l >> 4)*8 + j;
  int n  = l & 15;
  int jc = c4*16 + n;
  float w;
  if (g == 0)      w = (k < 64) ? W_ih[jc*64 + k]      : W_hh[jc*64 + (k-64)];
  else if (g == 1) w = (k < 64) ? W_ih[(64+jc)*64 + k] : W_hh[(64+jc)*64 + (k-64)];
  else if (g == 2) w = W_ih[(128+jc)*64 + k];
  else             w = W_hh[(128+jc)*64 + (k-64)];
  unsigned short hi = f2bf(w);
  unsigned short lo = f2bf(w - bf2f(hi));
  Bpk[q*512 + l*8 + j]         = hi;
  Bpk[24576 + q*512 + l*8 + j] = lo;
}

// Fused 12-step GRU + FC via split-bf16 MFMA. Wave = 32 nodes (two 16-row
// A-tiles sharing every B-fragment read -> half the LDS B-traffic per node,
// and tile0/tile1 interleave doubles MFMA chain slack). 224 blocks = 1/CU.
__global__ __attribute__((amdgpu_waves_per_eu(1, 2))) __launch_bounds__(GBLOCK)
void gru_mfma_kernel(const float* __restrict__ rin,
                     const float* __restrict__ W_gcn, const float* __restrict__ b_gcn,
                     const unsigned short* __restrict__ Bpk,
                     const float* __restrict__ b_ih, const float* __restrict__ b_hh,
                     const float* __restrict__ W_fc, const float* __restrict__ b_fc,
                     float* __restrict__ out, int N){
  extern __shared__ char smem[];
  short* Bl  = (short*)smem;
  float* hl  = (float*)(smem + B_LDS_BYTES);
  float* wgl = (float*)(smem + B_LDS_BYTES + H_LDS_BYTES);

  {
    const int4* Bg = (const int4*)Bpk;
    int4* Bd = (int4*)smem;
    for (int i = threadIdx.x; i < 6144; i += GBLOCK)
      Bd[i] = Bg[i];
    if (threadIdx.x < 64){
      wgl[threadIdx.x]       = W_gcn[threadIdx.x];
      wgl[64 + threadIdx.x]  = W_gcn[64 + threadIdx.x];
      wgl[128 + threadIdx.x] = b_gcn[threadIdx.x];
    }
  }
  __syncthreads();

  int lane = threadIdx.x & 63;
  int wid  = threadIdx.x >> 6;
  int tile = blockIdx.x*GWPB + wid;
  int ntiles = (N + 31) >> 5;
  if (tile >= ntiles) return;
  int n0   = tile << 5;
  int quad = lane >> 4;
  int n16  = lane & 15;
  float* hw = hl + wid*(32*HSTR);

  for (int i = lane; i < 32*HSTR; i += 64) hw[i] = 0.f;

  float wfc = W_fc[lane], bfc = b_fc[0];
  float bR[4], bZ[4], bNi[4], bNh[4];
  #pragma unroll
  for (int c4 = 0; c4 < 4; ++c4){
    int jc = c4*16 + n16;
    bR[c4]  = b_ih[jc]      + b_hh[jc];
    bZ[c4]  = b_ih[64+jc]   + b_hh[64+jc];
    bNi[c4] = b_ih[128+jc];
    bNh[c4] = b_hh[128+jc];
  }

  floatx4 hreg[2][4];
  #pragma unroll
  for (int u = 0; u < 2; ++u)
    #pragma unroll
    for (int c4 = 0; c4 < 4; ++c4) hreg[u][c4] = (floatx4){0.f,0.f,0.f,0.f};

  int nnA = n0 + n16;        if (nnA > N-1) nnA = N-1;
  int nnB = n0 + 16 + n16;   if (nnB > N-1) nnB = N-1;
  const float* rbA = rin + (size_t)nnA*24;
  const float* rbB = rin + (size_t)nnB*24;
  float2 rcA = *(const float2*)rbA;
  float2 rcB = *(const float2*)rbB;

  #pragma unroll 1
  for (int t = 0; t < T_STEPS; ++t){
    float2 rnA = (t < T_STEPS-1) ? *(const float2*)(rbA + 2*(t+1)) : rcA;
    float2 rnB = (t < T_STEPS-1) ? *(const float2*)(rbB + 2*(t+1)) : rcB;

    short8 ahi[2][4], alo[2][4];
    // s half (k-tiles 0,1): computed directly in A-frag layout, both tiles
    #pragma unroll
    for (int kt = 0; kt < 2; ++kt){
      int j0 = kt*32 + quad*8;
      floatx4 g0a = *(floatx4*)&wgl[j0],       g0b = *(floatx4*)&wgl[j0+4];
      floatx4 g1a = *(floatx4*)&wgl[64 + j0],  g1b = *(floatx4*)&wgl[64 + j0+4];
      floatx4 bga = *(floatx4*)&wgl[128 + j0], bgb = *(floatx4*)&wgl[128 + j0+4];
      #pragma unroll
      for (int u = 0; u < 2; ++u){
        float r0 = u ? rcB.x : rcA.x;
        float r1 = u ? rcB.y : rcA.y;
        short8 h8, l8;
        #pragma unroll
        for (int j = 0; j < 4; ++j){
          float sv = fmaxf(fmaf(r0, g0a[j], fmaf(r1, g1a[j], bga[j])), 0.f);
          unsigned short hh = f2bf(sv);
          h8[j] = (short)hh; l8[j] = (short)f2bf(sv - bf2f(hh));
          float sw = fmaxf(fmaf(r0, g0b[j], fmaf(r1, g1b[j], bgb[j])), 0.f);
          unsigned short hv = f2bf(sw);
          h8[4+j] = (short)hv; l8[4+j] = (short)f2bf(sw - bf2f(hv));
        }
        ahi[u][kt] = h8; alo[u][kt] = l8;
      }
    }
    // h half (k-tiles 2,3): from per-wave LDS tile rows [u*16 + n16]
    #pragma unroll
    for (int kt = 2; kt < 4; ++kt){
      #pragma unroll
      for (int u = 0; u < 2; ++u){
        int base = (u*16 + n16)*HSTR + (kt-2)*32 + quad*8;
        floatx4 xa = *(floatx4*)&hw[base];
        floatx4 xb = *(floatx4*)&hw[base+4];
        short8 h8, l8;
        #pragma unroll
        for (int j = 0; j < 4; ++j){
          unsigned short ha = f2bf(xa[j]);
          h8[j] = (short)ha; l8[j] = (short)f2bf(xa[j] - bf2f(ha));
          unsigned short hb = f2bf(xb[j]);
          h8[4+j] = (short)hb; l8[4+j] = (short)f2bf(xb[j] - bf2f(hb));
        }
        ahi[u][kt] = h8; alo[u][kt] = l8;
      }
    }

    #pragma unroll
    for (int c4 = 0; c4 < 4; ++c4){
      floatx4 aR[2], aZ[2], aNi[2], aNh[2];
      #pragma unroll
      for (int u = 0; u < 2; ++u){
        aR[u]  = (floatx4){bR[c4], bR[c4], bR[c4], bR[c4]};
        aZ[u]  = (floatx4){bZ[c4], bZ[c4], bZ[c4], bZ[c4]};
        aNi[u] = (floatx4){bNi[c4],bNi[c4],bNi[c4],bNi[c4]};
        aNh[u] = (floatx4){bNh[c4],bNh[c4],bNh[c4],bNh[c4]};
      }
      #pragma unroll
      for (int kt = 0; kt < 4; ++kt){
        int qr = (c4<<2) + kt;
        short8 wh = *(short8*)&Bl[qr*512 + lane*8];
        short8 wl = *(short8*)&Bl[24576 + qr*512 + lane*8];
        aR[0] = __builtin_amdgcn_mfma_f32_16x16x32_bf16(ahi[0][kt], wh, aR[0], 0,0,0);
        aR[1] = __builtin_amdgcn_mfma_f32_16x16x32_bf16(ahi[1][kt], wh, aR[1], 0,0,0);
        aR[0] = __builtin_amdgcn_mfma_f32_16x16x32_bf16(alo[0][kt], wh, aR[0], 0,0,0);
        aR[1] = __builtin_amdgcn_mfma_f32_16x16x32_bf16(alo[1][kt], wh, aR[1], 0,0,0);
        aR[0] = __builtin_amdgcn_mfma_f32_16x16x32_bf16(ahi[0][kt], wl, aR[0], 0,0,0);
        aR[1] = __builtin_amdgcn_mfma_f32_16x16x32_bf16(ahi[1][kt], wl, aR[1], 0,0,0);
        int qz = 16 + (c4<<2) + kt;
        wh = *(short8*)&Bl[qz*512 + lane*8];
        wl = *(short8*)&Bl[24576 + qz*512 + lane*8];
        aZ[0] = __builtin_amdgcn_mfma_f32_16x16x32_bf16(ahi[0][kt], wh, aZ[0], 0,0,0);
        aZ[1] = __builtin_amdgcn_mfma_f32_16x16x32_bf16(ahi[1][kt], wh, aZ[1], 0,0,0);
        aZ[0] = __builtin_amdgcn_mfma_f32_16x16x32_bf16(alo[0][kt], wh, aZ[0], 0,0,0);
        aZ[1] = __builtin_amdgcn_mfma_f32_16x16x32_bf16(alo[1][kt], wh, aZ[1], 0,0,0);
        aZ[0] = __builtin_amdgcn_mfma_f32_16x16x32_bf16(ahi[0][kt], wl, aZ[0], 0,0,0);
        aZ[1] = __builtin_amdgcn_mfma_f32_16x16x32_bf16(ahi[1][kt], wl, aZ[1], 0,0,0);
        if (kt < 2){
          int qn = 32 + (c4<<1) + kt;
          wh = *(short8*)&Bl[qn*512 + lane*8];
          wl = *(short8*)&Bl[24576 + qn*512 + lane*8];
          aNi[0] = __builtin_amdgcn_mfma_f32_16x16x32_bf16(ahi[0][kt], wh, aNi[0], 0,0,0);
          aNi[1] = __builtin_amdgcn_mfma_f32_16x16x32_bf16(ahi[1][kt], wh, aNi[1], 0,0,0);
          aNi[0] = __builtin_amdgcn_mfma_f32_16x16x32_bf16(alo[0][kt], wh, aNi[0], 0,0,0);
          aNi[1] = __builtin_amdgcn_mfma_f32_16x16x32_bf16(alo[1][kt], wh, aNi[1], 0,0,0);
          aNi[0] = __builtin_amdgcn_mfma_f32_16x16x32_bf16(ahi[0][kt], wl, aNi[0], 0,0,0);
          aNi[1] = __builtin_amdgcn_mfma_f32_16x16x32_bf16(ahi[1][kt], wl, aNi[1], 0,0,0);
        } else {
          int qn = 40 + (c4<<1) + (kt-2);
          wh = *(short8*)&Bl[qn*512 + lane*8];
          wl = *(short8*)&Bl[24576 + qn*512 + lane*8];
          aNh[0] = __builtin_amdgcn_mfma_f32_16x16x32_bf16(ahi[0][kt], wh, aNh[0], 0,0,0);
          aNh[1] = __builtin_amdgcn_mfma_f32_16x16x32_bf16(ahi[1][kt], wh, aNh[1], 0,0,0);
          aNh[0] = __builtin_amdgcn_mfma_f32_16x16x32_bf16(alo[0][kt], wh, aNh[0], 0,0,0);
          aNh[1] = __builtin_amdgcn_mfma_f32_16x16x32_bf16(alo[1][kt], wh, aNh[1], 0,0,0);
          aNh[0] = __builtin_amdgcn_mfma_f32_16x16x32_bf16(ahi[0][kt], wl, aNh[0], 0,0,0);
          aNh[1] = __builtin_amdgcn_mfma_f32_16x16x32_bf16(ahi[1][kt], wl, aNh[1], 0,0,0);
        }
      }
      // epilogue: C/D row = quad*4+r (within tile), col = c4*16+n16
      #pragma unroll
      for (int u = 0; u < 2; ++u){
        #pragma unroll
        for (int r = 0; r < 4; ++r){
          float rg = sigmoidf_(aR[u][r]);
          float zg = sigmoidf_(aZ[u][r]);
          float ng = tanhf_(aNi[u][r] + rg*aNh[u][r]);
          float hn = (1.f - zg)*ng + zg*hreg[u][c4][r];
          hreg[u][c4][r] = hn;
          hw[(u*16 + quad*4 + r)*HSTR + c4*16 + n16] = hn;
        }
      }
    }
    rcA = rnA; rcB = rnB;
  }

  // FC epilogue over 32 rows
  #pragma unroll 1
  for (int m = 0; m < 32; ++m){
    float v = hw[m*HSTR + lane] * wfc;
    #pragma unroll
    for (int off = 32; off >= 1; off >>= 1) v += __shfl_xor(v, off, 64);
    int n = n0 + m;
    if (lane == 0 && n < N) out[n] = v + bfc;
  }
}

extern "C" void kernel_launch(void* const* d_in, const int* in_sizes, int n_in,
                              void* d_out, int out_size, void* d_ws, size_t ws_size,
                              hipStream_t stream){
  const float* x     = (const float*)d_in[0];
  const int*   ei    = (const int*)d_in[1];
  const float* W_gcn = (const float*)d_in[2];
  const float* b_gcn = (const float*)d_in[3];
  const float* W_ih  = (const float*)d_in[4];
  const float* W_hh  = (const float*)d_in[5];
  const float* b_ih  = (const float*)d_in[6];
  const float* b_hh  = (const float*)d_in[7];
  const float* W_fc  = (const float*)d_in[8];
  const float* b_fc  = (const float*)d_in[9];
  float* out = (float*)d_out;
  const int N = in_sizes[0] / (T_STEPS*2);
  const int E = in_sizes[1] / 2;
  const int NB1024 = (N + 1023) / 1024;

  char* p = (char*)d_ws;
  auto alloc = [&](size_t bytes)->char*{
    char* r = p; p += (bytes + 255) & ~(size_t)255; return r;
  };
  int*   cnt       = (int*)  alloc((size_t)N*4);
  int*   row_start = (int*)  alloc((size_t)(N+1)*4);
  int*   cursor    = (int*)  alloc((size_t)N*4);
  int*   csr       = (int*)  alloc((size_t)E*4);
  float* dinv      = (float*)alloc((size_t)N*4);
  int*   part      = (int*)  alloc((size_t)N*4);
  int*   bsum      = (int*)  alloc((size_t)NB1024*4);
  int*   bincl     = (int*)  alloc((size_t)NB1024*4);
  float* rin       = (float*)alloc((size_t)N*24*4);
  unsigned short* Bpk = (unsigned short*)alloc((size_t)49152*2);

  hipMemsetAsync(cnt, 0, (size_t)N*4, stream);
  count_kernel<<<(E+255)/256, 256, 0, stream>>>(ei, E, cnt);
  dinv_kernel<<<(N+255)/256, 256, 0, stream>>>(cnt, dinv, N);
  scan1_kernel<<<NB1024, 1024, 0, stream>>>(cnt, part, bsum, N);
  scan2_kernel<<<1, 64, 0, stream>>>(bsum, bincl, NB1024);
  scan3_kernel<<<(N+255)/256, 256, 0, stream>>>(part, bincl, cnt, row_start, cursor, N);
  fill_kernel<<<(E+255)/256, 256, 0, stream>>>(ei, E, cursor, csr);
  packB_kernel<<<(48*512+255)/256, 256, 0, stream>>>(W_ih, W_hh, Bpk);
  gather6_kernel<<<(N*6+255)/256, 256, 0, stream>>>(x, row_start, csr, dinv, rin, N);

  (void)hipFuncSetAttribute((const void*)gru_mfma_kernel,
                            hipFuncAttributeMaxDynamicSharedMemorySize, LDS_TOTAL);
  int ntiles = (N + 31) / 32;
  int blocks = (ntiles + GWPB - 1) / GWPB;
  gru_mfma_kernel<<<blocks, GBLOCK, LDS_TOTAL, stream>>>(rin, W_gcn, b_gcn, Bpk,
                                                         b_ih, b_hh, W_fc, b_fc, out, N);
}

// Round 9
// 364.788 us; speedup vs baseline: 3.2033x; 1.0086x over previous
//
#include <hip/hip_runtime.h>
#include <math.h>

#define T_STEPS 12
#define HID 64
#define GWPB 7              // waves per block
#define GBLOCK (GWPB*64)    // 448 threads
#define HSTR 68             // h-tile row stride in u32 (64 data + 4 pad; 2-way banks = free)
#define B_LDS_BYTES 98304   // 48 frag-slots x 1KB x {hi,lo}
#define H_LDS_BYTES (GWPB*32*HSTR*4)        // 60928
#define LDS_TOTAL (B_LDS_BYTES + H_LDS_BYTES)  // 159232 <= 163840

typedef __attribute__((ext_vector_type(8))) short short8;
typedef __attribute__((ext_vector_type(4))) float floatx4;

__device__ __forceinline__ unsigned prm(unsigned a, unsigned b, unsigned s){
  return __builtin_amdgcn_perm(a, b, s);
}
__device__ __forceinline__ float sigmoid2_(float x){
  return 1.0f/(1.0f + __expf(-x));
}
__device__ __forceinline__ float tanh2_(float x){
  return 1.0f - 2.0f/(1.0f + __expf(2.0f*x));   // exact at +-inf, 0 at 0
}
__device__ __forceinline__ unsigned short f2bf(float x){   // RNE (packB only)
  unsigned u = __float_as_uint(x);
  return (unsigned short)((u + 0x7FFFu + ((u >> 16) & 1u)) >> 16);
}
__device__ __forceinline__ float bf2f(unsigned short h){
  return __uint_as_float(((unsigned)h) << 16);
}

// --- CSR build ----------------------------------------------------------
__global__ void count_kernel(const int* __restrict__ ei, int E, int* __restrict__ cnt){
  int e = blockIdx.x*blockDim.x + threadIdx.x;
  if (e < E) atomicAdd(&cnt[ei[E + e]], 1);
}

// dinv + pre-scaled xs = dinv[n]*x[n][*]  (thread = node x float4-chunk)
__global__ void dinv_scale_kernel(const int* __restrict__ cnt, const float* __restrict__ x,
                                  float* __restrict__ dinv, float4* __restrict__ xs, int N){
  int tid = blockIdx.x*blockDim.x + threadIdx.x;
  if (tid >= N*6) return;
  int n = tid / 6;
  float dn = rsqrtf((float)cnt[n] + 1.0f);
  if ((tid - n*6) == 0) dinv[n] = dn;
  float4 v = ((const float4*)x)[tid];
  xs[tid] = make_float4(dn*v.x, dn*v.y, dn*v.z, dn*v.w);
}

__global__ void scan1_kernel(const int* __restrict__ cnt, int* __restrict__ part,
                             int* __restrict__ bsum, int N){
  __shared__ int sm[1024];
  int tid = threadIdx.x;
  int g = blockIdx.x*1024 + tid;
  int v = (g < N) ? cnt[g] : 0;
  sm[tid] = v; __syncthreads();
  for (int off = 1; off < 1024; off <<= 1){
    int t = (tid >= off) ? sm[tid-off] : 0;
    __syncthreads();
    sm[tid] += t;
    __syncthreads();
  }
  if (g < N) part[g] = sm[tid];
  if (tid == 1023) bsum[blockIdx.x] = sm[1023];
}
__global__ void scan2_kernel(const int* __restrict__ bsum, int* __restrict__ bincl, int nb){
  int lane = threadIdx.x;
  int v = (lane < nb) ? bsum[lane] : 0;
  #pragma unroll
  for (int off = 1; off < 64; off <<= 1){
    int u = __shfl_up(v, off, 64);
    if (lane >= off) v += u;
  }
  if (lane < nb) bincl[lane] = v;
}
__global__ void scan3_kernel(const int* __restrict__ part, const int* __restrict__ bincl,
                             const int* __restrict__ cnt, int* __restrict__ row_start,
                             int* __restrict__ cursor, int N){
  int g = blockIdx.x*blockDim.x + threadIdx.x;
  if (g < N){
    int b = g >> 10;
    int incl = part[g] + (b ? bincl[b-1] : 0);
    int excl = incl - cnt[g];
    row_start[g] = excl;
    cursor[g]    = excl;
    if (g == N-1) row_start[N] = incl;
  }
}
__global__ void fill_kernel(const int* __restrict__ ei, int E,
                            int* __restrict__ cursor, int* __restrict__ csr){
  int e = blockIdx.x*blockDim.x + threadIdx.x;
  if (e < E){
    int dst = ei[E + e];
    int pos = atomicAdd(&cursor[dst], 1);
    csr[pos] = ei[e];  // src
  }
}

// gather: rin = dn * (sum_src xs[src] + xs[n])   (xs pre-scaled by dinv[src])
__global__ void gather6_kernel(const float4* __restrict__ xs, const int* __restrict__ row_start,
                               const int* __restrict__ csr, const float* __restrict__ dinv,
                               float4* __restrict__ rin, int N){
  int tid = blockIdx.x*blockDim.x + threadIdx.x;
  if (tid >= N*6) return;
  int n = tid / 6;
  int q = tid - n*6;
  int s0 = row_start[n], s1 = row_start[n+1];
  float4 acc = xs[n*6 + q];          // self term
  int e = s0;
  for (; e + 1 < s1; e += 2){
    int sa = csr[e], sb = csr[e+1];
    float4 va = xs[sa*6 + q];
    float4 vb = xs[sb*6 + q];
    acc.x += va.x + vb.x;
    acc.y += va.y + vb.y;
    acc.z += va.z + vb.z;
    acc.w += va.w + vb.w;
  }
  if (e < s1){
    float4 va = xs[csr[e]*6 + q];
    acc.x += va.x; acc.y += va.y; acc.z += va.z; acc.w += va.w;
  }
  float dn = dinv[n];
  rin[tid] = make_float4(dn*acc.x, dn*acc.y, dn*acc.z, dn*acc.w);
}

// Pack weights into split-bf16 B-fragment layout (round-6 proven layout).
__global__ void packB_kernel(const float* __restrict__ W_ih, const float* __restrict__ W_hh,
                             unsigned short* __restrict__ Bpk){
  int idx = blockIdx.x*blockDim.x + threadIdx.x;
  if (idx >= 48*512) return;
  int q = idx >> 9;
  int rr = idx & 511;
  int l = rr >> 3, j = rr & 7;
  int g, c4, kt;
  if (q < 32){ g = q >> 4; int rem = q & 15; c4 = rem >> 2; kt = rem & 3; }
  else if (q < 40){ g = 2; c4 = (q-32) >> 1; kt = (q-32) & 1; }
  else            { g = 3; c4 = (q-40) >> 1; kt = ((q-40) & 1) + 2; }
  int k  = kt*32 + (l >> 4)*8 + j;
  int n  = l & 15;
  int jc = c4*16 + n;
  float w;
  if (g == 0)      w = (k < 64) ? W_ih[jc*64 + k]      : W_hh[jc*64 + (k-64)];
  else if (g == 1) w = (k < 64) ? W_ih[(64+jc)*64 + k] : W_hh[(64+jc)*64 + (k-64)];
  else if (g == 2) w = W_ih[(128+jc)*64 + k];
  else             w = W_hh[(128+jc)*64 + (k-64)];
  unsigned short hi = f2bf(w);
  unsigned short lo = f2bf(w - bf2f(hi));
  Bpk[q*512 + l*8 + j]         = hi;
  Bpk[24576 + q*512 + l*8 + j] = lo;
}

// Fused 12-step GRU + FC via split-bf16 MFMA. Wave = 32 nodes (two 16-row
// A-tiles sharing all B reads). h stored in LDS PRE-PACKED (bf16hi|bf16lo per
// u32): conversion paid once at epilogue (4 VALU/elem), read side = 1 perm/elem.
// W_gcn/b_gcn hoisted to registers (kills 12 b128 LDS reads per t).
__global__ __attribute__((amdgpu_waves_per_eu(1, 2))) __launch_bounds__(GBLOCK)
void gru_mfma_kernel(const float* __restrict__ rin,
                     const float* __restrict__ W_gcn, const float* __restrict__ b_gcn,
                     const unsigned short* __restrict__ Bpk,
                     const float* __restrict__ b_ih, const float* __restrict__ b_hh,
                     const float* __restrict__ W_fc, const float* __restrict__ b_fc,
                     float* __restrict__ out, int N, int ntiles){
  extern __shared__ char smem[];
  short*    Bl  = (short*)smem;
  unsigned* hl  = (unsigned*)(smem + B_LDS_BYTES);

  {
    const int4* Bg = (const int4*)Bpk;
    int4* Bd = (int4*)smem;
    for (int i = threadIdx.x; i < 6144; i += GBLOCK) Bd[i] = Bg[i];
  }
  __syncthreads();

  int lane = threadIdx.x & 63;
  int wid  = threadIdx.x >> 6;
  int tile = wid*gridDim.x + blockIdx.x;   // balanced: every block gets 6-7 active waves
  if (tile >= ntiles) return;
  int n0   = tile << 5;
  int quad = lane >> 4;
  int n16  = lane & 15;
  unsigned* hwp = hl + wid*(32*HSTR);

  for (int i = lane; i < 32*HSTR; i += 64) hwp[i] = 0u;

  // hoisted GCN weights (loop-invariant; 12 x float4 regs)
  floatx4 g0a[2], g0b[2], g1a[2], g1b[2], bga[2], bgb[2];
  #pragma unroll
  for (int kt = 0; kt < 2; ++kt){
    int j0 = kt*32 + quad*8;
    g0a[kt] = *(const floatx4*)&W_gcn[j0];
    g0b[kt] = *(const floatx4*)&W_gcn[j0+4];
    g1a[kt] = *(const floatx4*)&W_gcn[64+j0];
    g1b[kt] = *(const floatx4*)&W_gcn[64+j0+4];
    bga[kt] = *(const floatx4*)&b_gcn[j0];
    bgb[kt] = *(const floatx4*)&b_gcn[j0+4];
  }

  float wfc = W_fc[lane], bfc = b_fc[0];
  float bR[4], bZ[4], bNi[4], bNh[4];
  #pragma unroll
  for (int c4 = 0; c4 < 4; ++c4){
    int jc = c4*16 + n16;
    bR[c4]  = b_ih[jc]      + b_hh[jc];
    bZ[c4]  = b_ih[64+jc]   + b_hh[64+jc];
    bNi[c4] = b_ih[128+jc];
    bNh[c4] = b_hh[128+jc];
  }

  floatx4 hreg[2][4];
  #pragma unroll
  for (int u = 0; u < 2; ++u)
    #pragma unroll
    for (int c4 = 0; c4 < 4; ++c4) hreg[u][c4] = (floatx4){0.f,0.f,0.f,0.f};

  int nnA = n0 + n16;        if (nnA > N-1) nnA = N-1;
  int nnB = n0 + 16 + n16;   if (nnB > N-1) nnB = N-1;
  const float* rbA = rin + (size_t)nnA*24;
  const float* rbB = rin + (size_t)nnB*24;
  float2 rcA = *(const float2*)rbA;
  float2 rcB = *(const float2*)rbB;

  #pragma unroll 1
  for (int t = 0; t < T_STEPS; ++t){
    float2 rnA = (t < T_STEPS-1) ? *(const float2*)(rbA + 2*(t+1)) : rcA;
    float2 rnB = (t < T_STEPS-1) ? *(const float2*)(rbB + 2*(t+1)) : rcB;

    short8 ahi[2][4], alo[2][4];
    // s half (k-tiles 0,1): compute in A-frag layout, trunc-hi + RHU-lo split
    #pragma unroll
    for (int kt = 0; kt < 2; ++kt){
      #pragma unroll
      for (int u = 0; u < 2; ++u){
        float r0 = u ? rcB.x : rcA.x;
        float r1 = u ? rcB.y : rcA.y;
        float f[8];
        #pragma unroll
        for (int j = 0; j < 4; ++j){
          f[j]   = fmaxf(fmaf(r0, g0a[kt][j], fmaf(r1, g1a[kt][j], bga[kt][j])), 0.f);
          f[4+j] = fmaxf(fmaf(r0, g0b[kt][j], fmaf(r1, g1b[kt][j], bgb[kt][j])), 0.f);
        }
        union { short8 v; unsigned w[4]; } H, L;
        #pragma unroll
        for (int p2 = 0; p2 < 4; ++p2){
          unsigned ua = __float_as_uint(f[2*p2]);
          unsigned ub = __float_as_uint(f[2*p2+1]);
          H.w[p2] = prm(ub, ua, 0x07060302u);
          unsigned ra = __float_as_uint(f[2*p2]   - __uint_as_float(ua & 0xFFFF0000u)) + 0x8000u;
          unsigned rb = __float_as_uint(f[2*p2+1] - __uint_as_float(ub & 0xFFFF0000u)) + 0x8000u;
          L.w[p2] = prm(rb, ra, 0x07060302u);
        }
        ahi[u][kt] = H.v; alo[u][kt] = L.v;
      }
    }
    // h half (k-tiles 2,3): packed u32 from LDS, 1 perm/element unpack
    #pragma unroll
    for (int kt = 2; kt < 4; ++kt){
      #pragma unroll
      for (int u = 0; u < 2; ++u){
        int base = (u*16 + n16)*HSTR + (kt-2)*32 + quad*8;
        uint4 wa = *(const uint4*)&hwp[base];
        uint4 wb = *(const uint4*)&hwp[base+4];
        union { short8 v; unsigned w[4]; } H, L;
        H.w[0] = prm(wa.y, wa.x, 0x07060302u); L.w[0] = prm(wa.y, wa.x, 0x05040100u);
        H.w[1] = prm(wa.w, wa.z, 0x07060302u); L.w[1] = prm(wa.w, wa.z, 0x05040100u);
        H.w[2] = prm(wb.y, wb.x, 0x07060302u); L.w[2] = prm(wb.y, wb.x, 0x05040100u);
        H.w[3] = prm(wb.w, wb.z, 0x07060302u); L.w[3] = prm(wb.w, wb.z, 0x05040100u);
        ahi[u][kt] = H.v; alo[u][kt] = L.v;
      }
    }

    #pragma unroll
    for (int c4 = 0; c4 < 4; ++c4){
      floatx4 aR[2], aZ[2], aNi[2], aNh[2];
      #pragma unroll
      for (int u = 0; u < 2; ++u){
        aR[u]  = (floatx4){bR[c4], bR[c4], bR[c4], bR[c4]};
        aZ[u]  = (floatx4){bZ[c4], bZ[c4], bZ[c4], bZ[c4]};
        aNi[u] = (floatx4){bNi[c4],bNi[c4],bNi[c4],bNi[c4]};
        aNh[u] = (floatx4){bNh[c4],bNh[c4],bNh[c4],bNh[c4]};
      }
      #pragma unroll
      for (int kt = 0; kt < 4; ++kt){
        int qr = (c4<<2) + kt;
        short8 wh = *(short8*)&Bl[qr*512 + lane*8];
        short8 wl = *(short8*)&Bl[24576 + qr*512 + lane*8];
        aR[0] = __builtin_amdgcn_mfma_f32_16x16x32_bf16(ahi[0][kt], wh, aR[0], 0,0,0);
        aR[1] = __builtin_amdgcn_mfma_f32_16x16x32_bf16(ahi[1][kt], wh, aR[1], 0,0,0);
        aR[0] = __builtin_amdgcn_mfma_f32_16x16x32_bf16(alo[0][kt], wh, aR[0], 0,0,0);
        aR[1] = __builtin_amdgcn_mfma_f32_16x16x32_bf16(alo[1][kt], wh, aR[1], 0,0,0);
        aR[0] = __builtin_amdgcn_mfma_f32_16x16x32_bf16(ahi[0][kt], wl, aR[0], 0,0,0);
        aR[1] = __builtin_amdgcn_mfma_f32_16x16x32_bf16(ahi[1][kt], wl, aR[1], 0,0,0);
        int qz = 16 + (c4<<2) + kt;
        wh = *(short8*)&Bl[qz*512 + lane*8];
        wl = *(short8*)&Bl[24576 + qz*512 + lane*8];
        aZ[0] = __builtin_amdgcn_mfma_f32_16x16x32_bf16(ahi[0][kt], wh, aZ[0], 0,0,0);
        aZ[1] = __builtin_amdgcn_mfma_f32_16x16x32_bf16(ahi[1][kt], wh, aZ[1], 0,0,0);
        aZ[0] = __builtin_amdgcn_mfma_f32_16x16x32_bf16(alo[0][kt], wh, aZ[0], 0,0,0);
        aZ[1] = __builtin_amdgcn_mfma_f32_16x16x32_bf16(alo[1][kt], wh, aZ[1], 0,0,0);
        aZ[0] = __builtin_amdgcn_mfma_f32_16x16x32_bf16(ahi[0][kt], wl, aZ[0], 0,0,0);
        aZ[1] = __builtin_amdgcn_mfma_f32_16x16x32_bf16(ahi[1][kt], wl, aZ[1], 0,0,0);
        if (kt < 2){
          int qn = 32 + (c4<<1) + kt;
          wh = *(short8*)&Bl[qn*512 + lane*8];
          wl = *(short8*)&Bl[24576 + qn*512 + lane*8];
          aNi[0] = __builtin_amdgcn_mfma_f32_16x16x32_bf16(ahi[0][kt], wh, aNi[0], 0,0,0);
          aNi[1] = __builtin_amdgcn_mfma_f32_16x16x32_bf16(ahi[1][kt], wh, aNi[1], 0,0,0);
          aNi[0] = __builtin_amdgcn_mfma_f32_16x16x32_bf16(alo[0][kt], wh, aNi[0], 0,0,0);
          aNi[1] = __builtin_amdgcn_mfma_f32_16x16x32_bf16(alo[1][kt], wh, aNi[1], 0,0,0);
          aNi[0] = __builtin_amdgcn_mfma_f32_16x16x32_bf16(ahi[0][kt], wl, aNi[0], 0,0,0);
          aNi[1] = __builtin_amdgcn_mfma_f32_16x16x32_bf16(ahi[1][kt], wl, aNi[1], 0,0,0);
        } else {
          int qn = 40 + (c4<<1) + (kt-2);
          wh = *(short8*)&Bl[qn*512 + lane*8];
          wl = *(short8*)&Bl[24576 + qn*512 + lane*8];
          aNh[0] = __builtin_amdgcn_mfma_f32_16x16x32_bf16(ahi[0][kt], wh, aNh[0], 0,0,0);
          aNh[1] = __builtin_amdgcn_mfma_f32_16x16x32_bf16(ahi[1][kt], wh, aNh[1], 0,0,0);
          aNh[0] = __builtin_amdgcn_mfma_f32_16x16x32_bf16(alo[0][kt], wh, aNh[0], 0,0,0);
          aNh[1] = __builtin_amdgcn_mfma_f32_16x16x32_bf16(alo[1][kt], wh, aNh[1], 0,0,0);
          aNh[0] = __builtin_amdgcn_mfma_f32_16x16x32_bf16(ahi[0][kt], wl, aNh[0], 0,0,0);
          aNh[1] = __builtin_amdgcn_mfma_f32_16x16x32_bf16(ahi[1][kt], wl, aNh[1], 0,0,0);
        }
      }
      // epilogue: C/D row = quad*4+r (within tile), col = c4*16+n16
      #pragma unroll
      for (int u = 0; u < 2; ++u){
        #pragma unroll
        for (int r = 0; r < 4; ++r){
          float rg = sigmoid2_(aR[u][r]);
          float zg = sigmoid2_(aZ[u][r]);
          float ng = tanh2_(aNi[u][r] + rg*aNh[u][r]);
          float hn = (1.f - zg)*ng + zg*hreg[u][c4][r];
          hreg[u][c4][r] = hn;
          unsigned hu = __float_as_uint(hn);
          float    rs = hn - __uint_as_float(hu & 0xFFFF0000u);
          unsigned rp = __float_as_uint(rs) + 0x8000u;
          hwp[(u*16 + quad*4 + r)*HSTR + c4*16 + n16] = prm(hu, rp, 0x07060302u);
        }
      }
    }
    rcA = rnA; rcB = rnB;
  }

  // FC epilogue over 32 rows (reconstruct h = hi + lo from packed word)
  #pragma unroll 1
  for (int m = 0; m < 32; ++m){
    unsigned w = hwp[m*HSTR + lane];
    float hv = __uint_as_float(w & 0xFFFF0000u) + __uint_as_float(w << 16);
    float v = hv * wfc;
    #pragma unroll
    for (int off = 32; off >= 1; off >>= 1) v += __shfl_xor(v, off, 64);
    int n = n0 + m;
    if (lane == 0 && n < N) out[n] = v + bfc;
  }
}

extern "C" void kernel_launch(void* const* d_in, const int* in_sizes, int n_in,
                              void* d_out, int out_size, void* d_ws, size_t ws_size,
                              hipStream_t stream){
  const float* x     = (const float*)d_in[0];
  const int*   ei    = (const int*)d_in[1];
  const float* W_gcn = (const float*)d_in[2];
  const float* b_gcn = (const float*)d_in[3];
  const float* W_ih  = (const float*)d_in[4];
  const float* W_hh  = (const float*)d_in[5];
  const float* b_ih  = (const float*)d_in[6];
  const float* b_hh  = (const float*)d_in[7];
  const float* W_fc  = (const float*)d_in[8];
  const float* b_fc  = (const float*)d_in[9];
  float* out = (float*)d_out;
  const int N = in_sizes[0] / (T_STEPS*2);
  const int E = in_sizes[1] / 2;
  const int NB1024 = (N + 1023) / 1024;

  char* p = (char*)d_ws;
  auto alloc = [&](size_t bytes)->char*{
    char* r = p; p += (bytes + 255) & ~(size_t)255; return r;
  };
  int*   cnt       = (int*)  alloc((size_t)N*4);
  int*   row_start = (int*)  alloc((size_t)(N+1)*4);
  int*   cursor    = (int*)  alloc((size_t)N*4);
  int*   csr       = (int*)  alloc((size_t)E*4);
  float* dinv      = (float*)alloc((size_t)N*4);
  int*   part      = (int*)  alloc((size_t)N*4);
  int*   bsum      = (int*)  alloc((size_t)NB1024*4);
  int*   bincl     = (int*)  alloc((size_t)NB1024*4);
  float* rin       = (float*)alloc((size_t)N*24*4);
  float* xs        = (float*)alloc((size_t)N*24*4);
  unsigned short* Bpk = (unsigned short*)alloc((size_t)49152*2);

  hipMemsetAsync(cnt, 0, (size_t)N*4, stream);
  count_kernel<<<(E+255)/256, 256, 0, stream>>>(ei, E, cnt);
  dinv_scale_kernel<<<(N*6+255)/256, 256, 0, stream>>>(cnt, x, dinv, (float4*)xs, N);
  scan1_kernel<<<NB1024, 1024, 0, stream>>>(cnt, part, bsum, N);
  scan2_kernel<<<1, 64, 0, stream>>>(bsum, bincl, NB1024);
  scan3_kernel<<<(N+255)/256, 256, 0, stream>>>(part, bincl, cnt, row_start, cursor, N);
  fill_kernel<<<(E+255)/256, 256, 0, stream>>>(ei, E, cursor, csr);
  packB_kernel<<<(48*512+255)/256, 256, 0, stream>>>(W_ih, W_hh, Bpk);
  gather6_kernel<<<(N*6+255)/256, 256, 0, stream>>>((const float4*)xs, row_start, csr,
                                                    dinv, (float4*)rin, N);

  (void)hipFuncSetAttribute((const void*)gru_mfma_kernel,
                            hipFuncAttributeMaxDynamicSharedMemorySize, LDS_TOTAL);
  int ntiles = (N + 31) / 32;
  int blocks = 256;
  if (ntiles < blocks) blocks = ntiles;
  gru_mfma_kernel<<<blocks, GBLOCK, LDS_TOTAL, stream>>>(rin, W_gcn, b_gcn, Bpk,
                                                         b_ih, b_hh, W_fc, b_fc,
                                                         out, N, ntiles);
}